// Round 1
// 84.510 us; speedup vs baseline: 1.0271x; 1.0271x over previous
//
#include <hip/hip_runtime.h>
#include <stdint.h>

#define TT 384   // num directions
#define NN 384   // num points
#define RR 384   // resolution
#define D1 128
#define D2 32

// sigmoid(500y) == 1.0f (f32) for y >= 17.33/500; < 2.3e-8 for y <= -17.6/500.
#define THETA 0.0352f
#define HALF_SLOTS 191.5f          // 383/2: r(x) = (x+1)*191.5
#define BAND_ITERS 14              // ceil(2*THETA*191.5) = 14

// ---------------- Threefry-2x32 (JAX partitionable), key = (0, 42) ----------------
__device__ inline void threefry2x32(uint32_t k0, uint32_t k1,
                                    uint32_t x0, uint32_t x1,
                                    uint32_t& o0, uint32_t& o1) {
    uint32_t ks2 = k0 ^ k1 ^ 0x1BD11BDAu;
    x0 += k0; x1 += k1;
    #define TF_ROUND(r) { x0 += x1; x1 = (x1 << (r)) | (x1 >> (32 - (r))); x1 ^= x0; }
    TF_ROUND(13) TF_ROUND(15) TF_ROUND(26) TF_ROUND(6)
    x0 += k1;  x1 += ks2 + 1u;
    TF_ROUND(17) TF_ROUND(29) TF_ROUND(16) TF_ROUND(24)
    x0 += ks2; x1 += k0 + 2u;
    TF_ROUND(13) TF_ROUND(15) TF_ROUND(26) TF_ROUND(6)
    x0 += k0;  x1 += k1 + 3u;
    TF_ROUND(17) TF_ROUND(29) TF_ROUND(16) TF_ROUND(24)
    x0 += k1;  x1 += ks2 + 4u;
    TF_ROUND(13) TF_ROUND(15) TF_ROUND(26) TF_ROUND(6)
    x0 += ks2; x1 += k0 + 5u;
    #undef TF_ROUND
    o0 = x0; o1 = x1;
}

// XLA f32 erf_inv (Giles polynomial)
__device__ inline float erfinv_f32(float x) {
    float w = -log1pf(-x * x);
    float p;
    if (w < 5.0f) {
        w = w - 2.5f;
        p =            2.81022636e-08f;
        p = fmaf(p, w, 3.43273939e-07f);
        p = fmaf(p, w, -3.5233877e-06f);
        p = fmaf(p, w, -4.39150654e-06f);
        p = fmaf(p, w, 0.00021858087f);
        p = fmaf(p, w, -0.00125372503f);
        p = fmaf(p, w, -0.00417768164f);
        p = fmaf(p, w, 0.246640727f);
        p = fmaf(p, w, 1.50140941f);
    } else {
        w = sqrtf(w) - 3.0f;
        p =            -0.000200214257f;
        p = fmaf(p, w, 0.000100950558f);
        p = fmaf(p, w, 0.00134934322f);
        p = fmaf(p, w, -0.00367342844f);
        p = fmaf(p, w, 0.00573950773f);
        p = fmaf(p, w, -0.0076224613f);
        p = fmaf(p, w, 0.00943887047f);
        p = fmaf(p, w, 1.00167406f);
        p = fmaf(p, w, 2.83297682f);
    }
    return p * x;
}

__device__ inline float bits_to_normal(uint32_t bits) {
    uint32_t fb = (bits >> 9) | 0x3F800000u;
    float f = __uint_as_float(fb) - 1.0f;               // [0, 1)
    float lo = __uint_as_float(0xBF7FFFFFu);            // nextafter(-1, 0)
    float u = f * 2.0f + lo;
    u = fmaxf(lo, u);
    return 1.41421356237f * erfinv_f32(u);
}

// Zero the loss accumulator. Replaces the old 240-block transpose kernel:
// the transpose is gone (GEMV now reads row-major x coalesced via
// lanes-over-k float4 loads), so this node is trivial.
__global__ void zero_out_k(float* __restrict__ out) {
    if (threadIdx.x == 0) out[0] = 0.0f;
}

// Scatter one point's contribution (sign = +1 for space1, -1 for space2) into
// the difference histograms. step part: +sgn at r1 (prefix-summed later);
// band part: sgn * sigmoid at the ~14 r in the transition band.
__device__ inline void scatter_point(float p, float sgn,
                                     float* __restrict__ inc,
                                     float* __restrict__ band) {
    int r1  = (int)ceilf((p + (1.0f + THETA)) * HALF_SLOTS); // first r: lin_r >= p+theta
    int rlo = (int)ceilf((p + (1.0f - THETA)) * HALF_SLOTS); // first r: lin_r >= p-theta
    if (r1 <= 0)        atomicAdd(&inc[0], sgn);
    else if (r1 <= 383) atomicAdd(&inc[r1], sgn);
    #pragma unroll
    for (int j = 0; j < BAND_ITERS; ++j) {
        int r = rlo + j;
        if (r >= 0 && r < r1 && r < RR) {
            float lin = -1.0f + 2.0f * (float)r / 383.0f;
            float sig = __builtin_amdgcn_rcpf(1.0f + __expf(500.0f * (p - lin)));
            atomicAdd(&band[r], sgn * sig);
        }
    }
}

// Fully fused: one block per direction t. 384 threads.
// Phase 1: RNG + normalize both direction columns (160 normals).
// Phase 2: GEMV directly on row-major x (NO transpose): lanes span k, so a
//   wave-wide float4 load covers 2 full rows of x1 (or 8 rows of x2) with
//   perfectly coalesced consecutive addresses. dot4 per lane, butterfly
//   shfl_xor reduce per row-group; iteration j's row sums are kept by the
//   matching lane, so after the loop each lane holds one row's projection
//   (the histogram is row-order-agnostic).
// Phase 3: histogram scatter + wave-shuffle prefix scan + loss reduce.
__global__ void __launch_bounds__(384) ect_fused(
        const float* __restrict__ x1, const float* __restrict__ x2,
        float* __restrict__ out) {
    int t = blockIdx.x;
    int tid = threadIdx.x;
    int lane = tid & 63;
    int w = tid >> 6;                 // wave id, 0..5
    __shared__ float v1s[D1];
    __shared__ float v2s[D2];
    __shared__ float inc[RR];
    __shared__ float band[RR];
    __shared__ float red[8];

    // ---- Phase 1: directions ----
    float g = 0.0f;
    if (tid < D1 + D2) {
        int i = (tid < D1) ? tid : tid - D1;
        uint32_t flat = (uint32_t)i * TT + (uint32_t)t;
        uint32_t o0, o1;
        threefry2x32(0u, 42u, 0u, flat, o0, o1);
        g = bits_to_normal(o0 ^ o1);
    }
    float sq = g * g;                 // waves 0,1 -> v1; wave 2 lanes<32 -> v2
    #pragma unroll
    for (int off = 32; off > 0; off >>= 1) sq += __shfl_xor(sq, off, 64);
    if (lane == 0) red[w] = sq;
    __syncthreads();
    float nrm1 = sqrtf(red[0] + red[1]);
    float nrm2 = sqrtf(red[2]);
    if (tid < D1)           v1s[tid] = g / nrm1;
    else if (tid < D1 + D2) v2s[tid - D1] = g / nrm2;
    inc[tid] = 0.0f;
    band[tid] = 0.0f;
    __syncthreads();

    // ---- Phase 2: coalesced row-major GEMV, lanes-over-k ----
    // v fragments: fixed per lane, hoisted out of the loops (one ds_read_b128).
    const float4* __restrict__ x1v = (const float4*)x1;
    const float4* __restrict__ x2v = (const float4*)x2;
    float4 vf1 = *(const float4*)&v1s[4 * (lane & 31)];   // k = 4*(lane&31)..+3
    float4 vf2 = *(const float4*)&v2s[4 * (lane & 7)];    // k = 4*(lane&7)..+3

    float p1 = 0.0f, p2 = 0.0f;

    // x1: row = 128 floats = 32 lanes * float4. One load instr = rows (2j, 2j+1).
    // float4 index: (w*64 + 2j + (lane>>5))*32 + (lane&31) = base1 + 64*j.
    int base1 = (w * 64 + (lane >> 5)) * 32 + (lane & 31);
    #pragma unroll 8
    for (int j = 0; j < 32; ++j) {
        float4 xv = x1v[base1 + 64 * j];
        float s = xv.x * vf1.x;
        s = fmaf(xv.y, vf1.y, s);
        s = fmaf(xv.z, vf1.z, s);
        s = fmaf(xv.w, vf1.w, s);
        #pragma unroll
        for (int m = 16; m > 0; m >>= 1) s += __shfl_xor(s, m, 64);  // sum per 32-half
        if ((lane & 31) == j) p1 = s;  // lane l ends with row w*64 + 2*(l&31) + (l>>5)
    }

    // x2: row = 32 floats = 8 lanes * float4. One load instr = rows 8j..8j+7.
    // float4 index: (w*64 + 8j + (lane>>3))*8 + (lane&7) = base2 + 64*j.
    int base2 = (w * 64 + (lane >> 3)) * 8 + (lane & 7);
    #pragma unroll
    for (int j = 0; j < 8; ++j) {
        float4 xv = x2v[base2 + 64 * j];
        float s = xv.x * vf2.x;
        s = fmaf(xv.y, vf2.y, s);
        s = fmaf(xv.z, vf2.z, s);
        s = fmaf(xv.w, vf2.w, s);
        #pragma unroll
        for (int m = 4; m > 0; m >>= 1) s += __shfl_xor(s, m, 64);   // sum per 8-group
        if ((lane & 7) == j) p2 = s;   // lane l ends with row w*64 + 8*(l&7) + (l>>3)
    }

    // ---- Phase 3: histogram (row assignment is a permutation; scatter is
    // order-agnostic, so each thread just scatters whatever rows it holds) ----
    scatter_point(p1,  1.0f, inc, band);
    scatter_point(p2, -1.0f, inc, band);
    __syncthreads();

    // inclusive prefix scan over inc[0..383]: wave shuffle scan + wave offsets
    float v = inc[tid];
    #pragma unroll
    for (int s = 1; s < 64; s <<= 1) {
        float u = __shfl_up(v, s, 64);
        if (lane >= s) v += u;
    }
    if (lane == 63) red[w] = v;       // wave totals
    __syncthreads();
    float off_acc = 0.0f;
    for (int j = 0; j < w; ++j) off_acc += red[j];
    v += off_acc;

    float d = v + band[tid];          // e1(r) - e2(r) at r = tid
    float s2 = d * d;
    #pragma unroll
    for (int off = 32; off > 0; off >>= 1) s2 += __shfl_xor(s2, off, 64);
    __syncthreads();                  // protect red[] reuse
    if (lane == 0) red[w] = s2;
    __syncthreads();
    if (tid == 0) {
        float s = red[0] + red[1] + red[2] + red[3] + red[4] + red[5];
        atomicAdd(out, s * (1.0f / ((float)RR * (float)TT)));
    }
}

extern "C" void kernel_launch(void* const* d_in, const int* in_sizes, int n_in,
                              void* d_out, int out_size, void* d_ws, size_t ws_size,
                              hipStream_t stream) {
    const float* space1 = (const float*)d_in[0];   // [384,128] row-major
    const float* space2 = (const float*)d_in[1];   // [384,32]  row-major
    float* out = (float*)d_out;

    // Workspace intentionally unused: no transpose pass anymore.
    (void)d_ws; (void)ws_size;

    zero_out_k<<<1, 64, 0, stream>>>(out);
    ect_fused<<<TT, 384, 0, stream>>>(space1, space2, out);
}